// Round 10
// baseline (85.601 us; speedup 1.0000x reference)
//
#include <hip/hip_runtime.h>

#define IH 512
#define IW 512
#define OH 502
#define OW 502
#define KS 11
#define HO 16                 /* output rows per strip */
#define NSTRIP 32             /* 32 strips of 16 rows */
#define NCH 48                /* 16*3 */
#define NBLK (NCH * NSTRIP)   /* 1536 */
#define NT 256                /* 256 threads * 2 cols = 512 cols */
#define LW 528                /* LDS row width (units); front pad 8 */
#define C1f 0.0001f
#define C2f 0.0009f

typedef float f32x2 __attribute__((ext_vector_type(2)));
typedef float f32x4 __attribute__((ext_vector_type(4)));
#define FMA2(a, b, c) __builtin_elementwise_fma((a), (b), (c))

// Gaussian(sigma=1.5, k=11), double-precision-derived. constexpr -> literals.
constexpr float G[KS] = {
    0.00102838f, 0.00759876f, 0.03600077f, 0.10936069f, 0.21300554f,
    0.26601173f, 0.21300554f, 0.10936069f, 0.03600077f, 0.00759876f,
    0.00102838f};

// Raw barrier: drain LDS ops but leave global prefetch loads in flight.
#define BARRIER() do {                                        \
    asm volatile("s_waitcnt lgkmcnt(0)" ::: "memory");        \
    __builtin_amdgcn_s_barrier();                             \
} while (0)

__global__ __launch_bounds__(NT, 2) void ssim_main(const float* __restrict__ x,
                                                   const float* __restrict__ y,
                                                   double* __restrict__ acc,
                                                   unsigned int* __restrict__ cnt,
                                                   float* __restrict__ out) {
    // Quantity-pair interleaved layouts so hblur packs over (mu_x,mu_y) and
    // (x2,y2): AB[col] = (s0,s1), CD[col] = (s2,s3), E[col] = s4.
    __shared__ f32x2 AB[2][LW];     /* 8448 B */
    __shared__ f32x2 CD[2][LW];     /* 8448 B */
    __shared__ float E[2][LW];      /* 4224 B */
    __shared__ float red[4];

    const int t = threadIdx.x;            // owns input cols 2t, 2t+1
    const int ch = blockIdx.x / NSTRIP;
    const int strip = blockIdx.x % NSTRIP;
    const int r0 = strip * HO;
    const float* __restrict__ xc = x + (size_t)ch * IH * IW + 2 * t;
    const float* __restrict__ yc = y + (size_t)ch * IH * IW + 2 * t;

    // ---- warmup: ring holds rows r0..r0+10; col-pair packed (x0,x1) ----
    f32x2 rx[KS], ry[KS];
#pragma unroll
    for (int i = 0; i < KS; ++i) {
        const int gr = min(r0 + i, IH - 1);
        rx[i] = *(const f32x2*)(xc + gr * IW);
        ry[i] = *(const f32x2*)(yc + gr * IW);
    }
    f32x2 nx0, ny0, nx1, ny1;
    {
        const int g0 = min(r0 + 11, IH - 1);
        const int g1 = min(r0 + 12, IH - 1);
        nx0 = *(const f32x2*)(xc + g0 * IW);
        ny0 = *(const f32x2*)(yc + g0 * IW);
        nx1 = *(const f32x2*)(xc + g1 * IW);
        ny1 = *(const f32x2*)(yc + g1 * IW);
    }

    float lsum = 0.f;

    for (int k = 0; k < HO / 2; ++k) {
        // ---- vblur rows A (ring[0..10]) and B (ring[1..10] + prefetch) ----
#pragma unroll
        for (int rr = 0; rr < 2; ++rr) {
            f32x2 s0 = {0.f, 0.f}, s1 = {0.f, 0.f}, s2 = {0.f, 0.f};
            f32x2 s3 = {0.f, 0.f}, s4 = {0.f, 0.f};
#pragma unroll
            for (int tp = 0; tp < KS; ++tp) {
                const f32x2 w2 = {G[tp], G[tp]};
                const f32x2 xv = (rr == 0) ? rx[tp]
                                : ((tp < KS - 1) ? rx[tp + 1] : nx0);
                const f32x2 yv = (rr == 0) ? ry[tp]
                                : ((tp < KS - 1) ? ry[tp + 1] : ny0);
                const f32x2 wx = w2 * xv;        // v_pk_mul_f32
                const f32x2 wy = w2 * yv;
                s0 = s0 + wx;                     // v_pk_add_f32
                s1 = s1 + wy;
                s2 = FMA2(wx, xv, s2);            // v_pk_fma_f32
                s3 = FMA2(wy, yv, s3);
                s4 = FMA2(wx, yv, s4);
            }
            // repack col-major -> quantity-pair interleave; one b128 + b128 + b64
            f32x4 w01 = {s0.x, s1.x, s0.y, s1.y};
            f32x4 w23 = {s2.x, s3.x, s2.y, s3.y};
            *(f32x4*)&AB[rr][2 * t + 8] = w01;
            *(f32x4*)&CD[rr][2 * t + 8] = w23;
            *(f32x2*)&E[rr][2 * t + 8] = s4;
        }
        BARRIER();   // barrier1: LDS writes visible; prefetch stays in flight

        // ---- shift ring by 2, commit prefetch, issue next prefetch now ----
#pragma unroll
        for (int i = 0; i < KS - 2; ++i) { rx[i] = rx[i + 2]; ry[i] = ry[i + 2]; }
        rx[KS - 2] = nx0; ry[KS - 2] = ny0;
        rx[KS - 1] = nx1; ry[KS - 1] = ny1;
        {
            const int g0 = min(r0 + 2 * k + 13, IH - 1);
            const int g1 = min(r0 + 2 * k + 14, IH - 1);
            nx0 = *(const f32x2*)(xc + g0 * IW);
            ny0 = *(const f32x2*)(yc + g0 * IW);
            nx1 = *(const f32x2*)(xc + g1 * IW);
            ny1 = *(const f32x2*)(yc + g1 * IW);
        }

        // ---- hblur + ssim: 2 rows x 128 4-col chunks ----
        {
            const int rr = t >> 7;            // wave-uniform
            const int c4 = (t & 127) * 4;
            const int orow = r0 + 2 * k + rr;

            f32x2 m01[4] = {{0.f,0.f},{0.f,0.f},{0.f,0.f},{0.f,0.f}};
            f32x2 m23[4] = {{0.f,0.f},{0.f,0.f},{0.f,0.f},{0.f,0.f}};
            float m4[4] = {0.f, 0.f, 0.f, 0.f};

            // AB then CD through one reused window buffer (contained live range)
#pragma unroll
            for (int h = 0; h < 2; ++h) {
                const f32x2* __restrict__ src = h ? &CD[rr][0] : &AB[rr][0];
                f32x2* mq = h ? m23 : m01;
                f32x2 fb[16];
#pragma unroll
                for (int a = 0; a < 8; ++a)
                    *(f32x4*)&fb[2 * a] = *(const f32x4*)&src[c4 + 2 + 2 * a];
#pragma unroll
                for (int cc = 0; cc < 4; ++cc) {
                    f32x2 m = {0.f, 0.f};
#pragma unroll
                    for (int tp = 0; tp < KS; ++tp) {
                        const f32x2 w2 = {G[tp], G[tp]};
                        m = FMA2(w2, fb[cc + 1 + tp], m);
                    }
                    mq[cc] = m;
                }
            }
            {
                float fe[20];
#pragma unroll
                for (int a = 0; a < 5; ++a)
                    *(f32x4*)&fe[4 * a] = *(const f32x4*)&E[rr][c4 + 4 * a];
#pragma unroll
                for (int cc = 0; cc < 4; ++cc) {
                    float s = 0.f;
#pragma unroll
                    for (int tp = 0; tp < KS; ++tp)
                        s = fmaf(G[tp], fe[cc + 3 + tp], s);
                    m4[cc] = s;
                }
            }

            if (orow < OH) {
#pragma unroll
                for (int cc = 0; cc < 4; ++cc) {
                    const int gc = c4 + cc;
                    if (gc < OW) {
                        const f32x2 p2 = m01[cc] * m01[cc];   // (mux2, muy2)
                        const float muxy = m01[cc].x * m01[cc].y;
                        const float cxy = m4[cc] - muxy;
                        const float t1 = fmaf(2.f, muxy, C1f);
                        const float t2 = fmaf(2.f, cxy, C2f);
                        const float num = t1 * t2;
                        const f32x2 v = m23[cc] - p2;         // (vx, vy)
                        const float sA = p2.x + p2.y + C1f;
                        const float sB = v.x + v.y + C2f;
                        const float den = sA * sB;
                        float r = __builtin_amdgcn_rcpf(den);
                        r = r * fmaf(-den, r, 2.0f);          // Newton step
                        lsum = fmaf(num, r, lsum);
                    }
                }
            }
        }
        BARRIER();   // barrier2: hblur reads done before next iter's writes
    }

    // ---- block reduce (4 waves of 64) + last-block finalize ----
#pragma unroll
    for (int off = 32; off > 0; off >>= 1) lsum += __shfl_down(lsum, off, 64);
    const int wave = t >> 6, lane = t & 63;
    if (lane == 0) red[wave] = lsum;
    __syncthreads();
    if (t == 0) {
        const float bs = (red[0] + red[1]) + (red[2] + red[3]);
        atomicAdd(acc, (double)bs);
        __threadfence();
        const unsigned int prev = atomicAdd(cnt, 1u);
        if (prev == (unsigned int)(NBLK - 1)) {
            const double total = atomicAdd(acc, 0.0);  // coherent read
            out[0] = (float)(1.0 - total / 12096192.0);  // 48*502*502
        }
    }
}

extern "C" void kernel_launch(void* const* d_in, const int* in_sizes, int n_in,
                              void* d_out, int out_size, void* d_ws, size_t ws_size,
                              hipStream_t stream) {
    const float* x = (const float*)d_in[0];
    const float* y = (const float*)d_in[1];
    float* out = (float*)d_out;
    double* acc = (double*)d_ws;
    unsigned int* cnt = (unsigned int*)((char*)d_ws + 8);

    hipMemsetAsync(d_ws, 0, 16, stream);
    ssim_main<<<NBLK, NT, 0, stream>>>(x, y, acc, cnt, out);
}